// Round 1
// baseline (724.431 us; speedup 1.0000x reference)
//
#include <hip/hip_runtime.h>

#define NFEAT 512
#define HID 16
#define NCLS 40

// ---------------- CSR build ----------------

__global__ void k_hist(const int* __restrict__ row, int* __restrict__ cnt, int E) {
    int i = blockIdx.x * blockDim.x + threadIdx.x;
    int stride = gridDim.x * blockDim.x;
    for (; i < E; i += stride) atomicAdd(&cnt[row[i]], 1);
}

// block=1024: per-block inclusive scan, write exclusive, emit block sums
__global__ void k_scan1(const int* __restrict__ cnt, int* __restrict__ start,
                        int* __restrict__ bsums, int n) {
    __shared__ int sm[1024];
    int i = blockIdx.x * 1024 + threadIdx.x;
    int v = (i < n) ? cnt[i] : 0;
    sm[threadIdx.x] = v;
    __syncthreads();
    for (int off = 1; off < 1024; off <<= 1) {
        int t = (threadIdx.x >= off) ? sm[threadIdx.x - off] : 0;
        __syncthreads();
        sm[threadIdx.x] += t;
        __syncthreads();
    }
    if (i < n) start[i] = sm[threadIdx.x] - v;   // exclusive
    if (threadIdx.x == 1023) bsums[blockIdx.x] = sm[1023];
}

// single block scans the (<=128) block sums, exclusive
__global__ void k_scan2(const int* __restrict__ bsums, int* __restrict__ boffs, int nb) {
    __shared__ int sm[128];
    int v = (threadIdx.x < nb) ? bsums[threadIdx.x] : 0;
    sm[threadIdx.x] = v;
    __syncthreads();
    for (int off = 1; off < 128; off <<= 1) {
        int t = (threadIdx.x >= off) ? sm[threadIdx.x - off] : 0;
        __syncthreads();
        sm[threadIdx.x] += t;
        __syncthreads();
    }
    if (threadIdx.x < nb) boffs[threadIdx.x] = sm[threadIdx.x] - v;
}

__global__ void k_scan3(const int* __restrict__ cnt, const int* __restrict__ boffs,
                        int* __restrict__ start, int* __restrict__ cursor,
                        float* __restrict__ dinv, int n, int E) {
    int i = blockIdx.x * 1024 + threadIdx.x;
    if (i >= n) return;
    int s = start[i] + boffs[blockIdx.x];
    start[i] = s;
    cursor[i] = s;
    dinv[i] = rsqrtf((float)cnt[i] + 1.0f);   // +1 = self loop
    if (i == 0) start[n] = E;
}

__global__ void k_scatter(const int* __restrict__ row, const int* __restrict__ col,
                          int* __restrict__ cursor, int* __restrict__ csr, int E) {
    int i = blockIdx.x * blockDim.x + threadIdx.x;
    int stride = gridDim.x * blockDim.x;
    for (; i < E; i += stride) {
        int r = row[i];
        int p = atomicAdd(&cursor[r], 1);
        csr[p] = col[i];
    }
}

// ---------------- layer 1 GEMM: h1 = x @ W1  (N x 512) @ (512 x 16) ----------------
// one thread per row; W1 indexed with thread-uniform constant offsets -> s_load path
__global__ __launch_bounds__(64) void k_gemm1(const float* __restrict__ x,
                                              const float* __restrict__ W,
                                              float* __restrict__ h1, int n) {
    int r = blockIdx.x * 64 + threadIdx.x;
    if (r >= n) return;
    const float* xr = x + (size_t)r * NFEAT;
    float acc[HID];
#pragma unroll
    for (int j = 0; j < HID; j++) acc[j] = 0.f;

    for (int h = 0; h < 8; h++) {            // 8 chunks of 64 floats
        float4 xv[16];
#pragma unroll
        for (int c = 0; c < 16; c++)
            xv[c] = reinterpret_cast<const float4*>(xr)[h * 16 + c];
#pragma unroll
        for (int c = 0; c < 16; c++) {
#pragma unroll
            for (int m = 0; m < 4; m++) {
                float xs = (&xv[c].x)[m];
                int k = h * 64 + c * 4 + m;
#pragma unroll
                for (int j = 0; j < HID; j++)
                    acc[j] = fmaf(xs, W[k * HID + j], acc[j]);
            }
        }
    }
    float4* o = reinterpret_cast<float4*>(h1 + (size_t)r * HID);
    o[0] = make_float4(acc[0], acc[1], acc[2], acc[3]);
    o[1] = make_float4(acc[4], acc[5], acc[6], acc[7]);
    o[2] = make_float4(acc[8], acc[9], acc[10], acc[11]);
    o[3] = make_float4(acc[12], acc[13], acc[14], acc[15]);
}

// ---------------- layer 1 aggregation + bias + relu ----------------
// 16 lanes per row (one feature per lane)
__global__ void k_agg1(const float* __restrict__ h1, const int* __restrict__ start,
                       const int* __restrict__ csr, const float* __restrict__ dinv,
                       const float* __restrict__ b1, float* __restrict__ h1b, int n) {
    int g = threadIdx.x >> 4;
    int j = threadIdx.x & 15;
    int r = blockIdx.x * 16 + g;
    if (r >= n) return;
    int s = start[r], e = start[r + 1];
    float acc = 0.f;
    for (int p = s; p < e; p++) {
        int c = csr[p];
        acc = fmaf(dinv[c], h1[c * HID + j], acc);
    }
    float dr = dinv[r];
    float z = dr * (acc + dr * h1[r * HID + j]) + b1[j];
    h1b[r * HID + j] = fmaxf(z, 0.f);
}

// ---------------- layer 2 GEMM: h2 = h1b @ W2  (N x 16) @ (16 x 40) ----------------
__global__ __launch_bounds__(64) void k_gemm2(const float* __restrict__ h1b,
                                              const float* __restrict__ W2,
                                              float* __restrict__ h2, int n) {
    int r = blockIdx.x * 64 + threadIdx.x;
    if (r >= n) return;
    float v[HID];
    const float4* hv = reinterpret_cast<const float4*>(h1b + (size_t)r * HID);
#pragma unroll
    for (int q = 0; q < 4; q++) {
        float4 t = hv[q];
        v[q * 4 + 0] = t.x; v[q * 4 + 1] = t.y; v[q * 4 + 2] = t.z; v[q * 4 + 3] = t.w;
    }
    float acc[NCLS];
#pragma unroll
    for (int j = 0; j < NCLS; j++) acc[j] = 0.f;
#pragma unroll
    for (int k = 0; k < HID; k++) {
#pragma unroll
        for (int j = 0; j < NCLS; j++)
            acc[j] = fmaf(v[k], W2[k * NCLS + j], acc[j]);
    }
    float4* o = reinterpret_cast<float4*>(h2 + (size_t)r * NCLS);
#pragma unroll
    for (int q = 0; q < 10; q++)
        o[q] = make_float4(acc[q * 4], acc[q * 4 + 1], acc[q * 4 + 2], acc[q * 4 + 3]);
}

// ---------------- layer 2 aggregation + bias + log_softmax ----------------
// 8 lanes per row, 5 features per lane (j = lane + 8*i)
__global__ void k_agg2(const float* __restrict__ h2, const int* __restrict__ start,
                       const int* __restrict__ csr, const float* __restrict__ dinv,
                       const float* __restrict__ b2, float* __restrict__ out, int n) {
    int g = threadIdx.x >> 3;
    int l = threadIdx.x & 7;
    int r = blockIdx.x * 32 + g;
    if (r >= n) return;
    int s = start[r], e = start[r + 1];
    float acc[5] = {0.f, 0.f, 0.f, 0.f, 0.f};
    for (int p = s; p < e; p++) {
        int c = csr[p];
        float w = dinv[c];
        const float* hc = h2 + (size_t)c * NCLS;
#pragma unroll
        for (int i = 0; i < 5; i++) acc[i] = fmaf(w, hc[l + 8 * i], acc[i]);
    }
    float dr = dinv[r];
    const float* hr = h2 + (size_t)r * NCLS;
    float z[5];
#pragma unroll
    for (int i = 0; i < 5; i++)
        z[i] = dr * (acc[i] + dr * hr[l + 8 * i]) + b2[l + 8 * i];

    float m = z[0];
#pragma unroll
    for (int i = 1; i < 5; i++) m = fmaxf(m, z[i]);
#pragma unroll
    for (int off = 1; off < 8; off <<= 1) m = fmaxf(m, __shfl_xor(m, off, 8));
    float ssum = 0.f;
#pragma unroll
    for (int i = 0; i < 5; i++) ssum += __expf(z[i] - m);
#pragma unroll
    for (int off = 1; off < 8; off <<= 1) ssum += __shfl_xor(ssum, off, 8);
    float ls = m + logf(ssum);
#pragma unroll
    for (int i = 0; i < 5; i++) out[(size_t)r * NCLS + l + 8 * i] = z[i] - ls;
}

// ---------------- launch ----------------

extern "C" void kernel_launch(void* const* d_in, const int* in_sizes, int n_in,
                              void* d_out, int out_size, void* d_ws, size_t ws_size,
                              hipStream_t stream) {
    const float* x  = (const float*)d_in[0];
    const int*   ei = (const int*)d_in[1];
    const float* W1 = (const float*)d_in[2];
    const float* b1 = (const float*)d_in[3];
    const float* W2 = (const float*)d_in[4];
    const float* b2 = (const float*)d_in[5];

    const int n = in_sizes[0] / NFEAT;   // 100000
    const int E = in_sizes[1] / 2;       // 3200000
    const int* row = ei;
    const int* col = ei + E;

    char* w = (char*)d_ws;
    auto alloc = [&](size_t bytes) {
        void* p = (void*)w;
        w += (bytes + 255) & ~(size_t)255;
        return p;
    };
    int*   cnt    = (int*)alloc((size_t)n * 4);
    int*   start  = (int*)alloc((size_t)(n + 1) * 4);
    int*   cursor = (int*)alloc((size_t)n * 4);
    int*   bsums  = (int*)alloc(512);
    int*   boffs  = (int*)alloc(512);
    float* dinv   = (float*)alloc((size_t)n * 4);
    int*   csr    = (int*)alloc((size_t)E * 4);
    float* h1     = (float*)alloc((size_t)n * HID * 4);
    float* h1b    = (float*)alloc((size_t)n * HID * 4);
    float* h2     = (float*)alloc((size_t)n * NCLS * 4);

    const int nb = (n + 1023) / 1024;    // 98

    hipMemsetAsync(cnt, 0, (size_t)n * 4, stream);
    k_hist<<<2048, 256, 0, stream>>>(row, cnt, E);
    k_scan1<<<nb, 1024, 0, stream>>>(cnt, start, bsums, n);
    k_scan2<<<1, 128, 0, stream>>>(bsums, boffs, nb);
    k_scan3<<<nb, 1024, 0, stream>>>(cnt, boffs, start, cursor, dinv, n, E);
    k_scatter<<<2048, 256, 0, stream>>>(row, col, cursor, csr, E);

    k_gemm1<<<(n + 63) / 64, 64, 0, stream>>>(x, W1, h1, n);
    k_agg1<<<(n + 15) / 16, 256, 0, stream>>>(h1, start, csr, dinv, b1, h1b, n);
    k_gemm2<<<(n + 63) / 64, 64, 0, stream>>>(h1b, W2, h2, n);
    k_agg2<<<(n + 31) / 32, 256, 0, stream>>>(h2, start, csr, dinv, b2, (float*)d_out, n);
}

// Round 2
// 526.682 us; speedup vs baseline: 1.3755x; 1.3755x over previous
//
#include <hip/hip_runtime.h>

#define NFEAT 512
#define HID 16
#define NCLS 40
#define BROWS 256   // rows per bucket; nb = ceil(n/256) = 391 <= 512 (LDS arrays sized 512)

// ---------------- degree histogram ----------------
__global__ void k_hist(const int* __restrict__ row, int* __restrict__ cnt, int E) {
    int i = blockIdx.x * blockDim.x + threadIdx.x;
    int stride = gridDim.x * blockDim.x;
    for (; i < E; i += stride) atomicAdd(&cnt[row[i]], 1);
}

// per-bucket edge counts + dinv (one block per 256 rows)
__global__ void k_bsum(const int* __restrict__ cnt, float* __restrict__ dinv,
                       int* __restrict__ bcnt, int n) {
    __shared__ int sm[256];
    int i = blockIdx.x * 256 + threadIdx.x;
    int c = (i < n) ? cnt[i] : 0;
    if (i < n) dinv[i] = rsqrtf((float)c + 1.0f);   // +1 = self loop
    sm[threadIdx.x] = c;
    __syncthreads();
    for (int off = 128; off > 0; off >>= 1) {
        if (threadIdx.x < off) sm[threadIdx.x] += sm[threadIdx.x + off];
        __syncthreads();
    }
    if (threadIdx.x == 0) bcnt[blockIdx.x] = sm[0];
}

// single-block exclusive scan of bucket counts (nb <= 512)
__global__ void k_scan_small(const int* __restrict__ bcnt, int* __restrict__ boff,
                             int* __restrict__ bcur, int nb, int E) {
    __shared__ int sm[512];
    int v = (threadIdx.x < nb) ? bcnt[threadIdx.x] : 0;
    sm[threadIdx.x] = v;
    __syncthreads();
    for (int off = 1; off < 512; off <<= 1) {
        int t = (threadIdx.x >= off) ? sm[threadIdx.x - off] : 0;
        __syncthreads();
        sm[threadIdx.x] += t;
        __syncthreads();
    }
    if (threadIdx.x < nb) {
        int e = sm[threadIdx.x] - v;
        boff[threadIdx.x] = e;
        bcur[threadIdx.x] = e;
    }
    if (threadIdx.x == 0) boff[nb] = E;
}

// ---------------- pass A: bin (row,col) pairs by bucket, LDS-aggregated cursors ----------------
__global__ __launch_bounds__(256) void k_pairs(const int* __restrict__ row,
                                               const int* __restrict__ col,
                                               int* __restrict__ bcur,
                                               int2* __restrict__ pairs, int E, int nb) {
    __shared__ int lhist[512];
    __shared__ int lbase[512];
    int chunk = (E + gridDim.x - 1) / gridDim.x;
    int s = blockIdx.x * chunk;
    int e = min(s + chunk, E);
    for (int b = threadIdx.x; b < nb; b += 256) lhist[b] = 0;
    __syncthreads();
    for (int i = s + threadIdx.x; i < e; i += 256)
        atomicAdd(&lhist[row[i] >> 8], 1);
    __syncthreads();
    for (int b = threadIdx.x; b < nb; b += 256) {
        int h = lhist[b];
        lbase[b] = h ? atomicAdd(&bcur[b], h) : 0;
        lhist[b] = 0;   // reuse as local cursor
    }
    __syncthreads();
    for (int i = s + threadIdx.x; i < e; i += 256) {
        int r = row[i], c = col[i];
        int b = r >> 8;
        int off = atomicAdd(&lhist[b], 1);
        pairs[lbase[b] + off] = make_int2(r, c);
    }
}

// ---------------- pass B: per-bucket CSR build (LDS cursors, L2-local writes) ----------------
__global__ __launch_bounds__(256) void k_csr(const int* __restrict__ cnt,
                                             const int* __restrict__ boff,
                                             const int2* __restrict__ pairs,
                                             int* __restrict__ csr, int* __restrict__ start,
                                             int n, int E) {
    __shared__ int sm[256];
    __shared__ int lcur[256];
    int b = blockIdx.x;
    int base = b * BROWS;
    int i = base + threadIdx.x;
    int c = (i < n) ? cnt[i] : 0;
    sm[threadIdx.x] = c;
    __syncthreads();
    for (int off = 1; off < 256; off <<= 1) {
        int t = (threadIdx.x >= off) ? sm[threadIdx.x - off] : 0;
        __syncthreads();
        sm[threadIdx.x] += t;
        __syncthreads();
    }
    int excl = sm[threadIdx.x] - c;   // exclusive within bucket
    lcur[threadIdx.x] = excl;
    int bo = boff[b];
    if (i < n) start[i] = bo + excl;
    if (b == 0 && threadIdx.x == 0) start[n] = E;
    __syncthreads();
    int e2 = boff[b + 1];
    for (int p = bo + (int)threadIdx.x; p < e2; p += 256) {
        int2 pr = pairs[p];
        int off = atomicAdd(&lcur[pr.x - base], 1);
        csr[bo + off] = pr.y;   // write inside bucket's ~32KB region -> L2-coalesced
    }
}

// ---------------- layer 1 GEMM: h1 = x @ W1  (N x 512) @ (512 x 16) ----------------
__global__ __launch_bounds__(64) void k_gemm1(const float* __restrict__ x,
                                              const float* __restrict__ W,
                                              float* __restrict__ h1, int n) {
    int r = blockIdx.x * 64 + threadIdx.x;
    if (r >= n) return;
    const float* xr = x + (size_t)r * NFEAT;
    float acc[HID];
#pragma unroll
    for (int j = 0; j < HID; j++) acc[j] = 0.f;

    for (int h = 0; h < 8; h++) {
        float4 xv[16];
#pragma unroll
        for (int c = 0; c < 16; c++)
            xv[c] = reinterpret_cast<const float4*>(xr)[h * 16 + c];
#pragma unroll
        for (int c = 0; c < 16; c++) {
#pragma unroll
            for (int m = 0; m < 4; m++) {
                float xs = (&xv[c].x)[m];
                int k = h * 64 + c * 4 + m;
#pragma unroll
                for (int j = 0; j < HID; j++)
                    acc[j] = fmaf(xs, W[k * HID + j], acc[j]);
            }
        }
    }
    float4* o = reinterpret_cast<float4*>(h1 + (size_t)r * HID);
    o[0] = make_float4(acc[0], acc[1], acc[2], acc[3]);
    o[1] = make_float4(acc[4], acc[5], acc[6], acc[7]);
    o[2] = make_float4(acc[8], acc[9], acc[10], acc[11]);
    o[3] = make_float4(acc[12], acc[13], acc[14], acc[15]);
}

// ---------------- layer 1 aggregation + bias + relu ----------------
__global__ void k_agg1(const float* __restrict__ h1, const int* __restrict__ start,
                       const int* __restrict__ csr, const float* __restrict__ dinv,
                       const float* __restrict__ b1, float* __restrict__ h1b, int n) {
    int g = threadIdx.x >> 4;
    int j = threadIdx.x & 15;
    int r = blockIdx.x * 16 + g;
    if (r >= n) return;
    int s = start[r], e = start[r + 1];
    float acc = 0.f;
    for (int p = s; p < e; p++) {
        int c = csr[p];
        acc = fmaf(dinv[c], h1[c * HID + j], acc);
    }
    float dr = dinv[r];
    float z = dr * (acc + dr * h1[r * HID + j]) + b1[j];
    h1b[r * HID + j] = fmaxf(z, 0.f);
}

// ---------------- layer 2 GEMM: h2 = h1b @ W2  (N x 16) @ (16 x 40) ----------------
__global__ __launch_bounds__(64) void k_gemm2(const float* __restrict__ h1b,
                                              const float* __restrict__ W2,
                                              float* __restrict__ h2, int n) {
    int r = blockIdx.x * 64 + threadIdx.x;
    if (r >= n) return;
    float v[HID];
    const float4* hv = reinterpret_cast<const float4*>(h1b + (size_t)r * HID);
#pragma unroll
    for (int q = 0; q < 4; q++) {
        float4 t = hv[q];
        v[q * 4 + 0] = t.x; v[q * 4 + 1] = t.y; v[q * 4 + 2] = t.z; v[q * 4 + 3] = t.w;
    }
    float acc[NCLS];
#pragma unroll
    for (int j = 0; j < NCLS; j++) acc[j] = 0.f;
#pragma unroll
    for (int k = 0; k < HID; k++) {
#pragma unroll
        for (int j = 0; j < NCLS; j++)
            acc[j] = fmaf(v[k], W2[k * NCLS + j], acc[j]);
    }
    float4* o = reinterpret_cast<float4*>(h2 + (size_t)r * NCLS);
#pragma unroll
    for (int q = 0; q < 10; q++)
        o[q] = make_float4(acc[q * 4], acc[q * 4 + 1], acc[q * 4 + 2], acc[q * 4 + 3]);
}

// ---------------- layer 2 aggregation + bias + log_softmax ----------------
__global__ void k_agg2(const float* __restrict__ h2, const int* __restrict__ start,
                       const int* __restrict__ csr, const float* __restrict__ dinv,
                       const float* __restrict__ b2, float* __restrict__ out, int n) {
    int g = threadIdx.x >> 3;
    int l = threadIdx.x & 7;
    int r = blockIdx.x * 32 + g;
    if (r >= n) return;
    int s = start[r], e = start[r + 1];
    float acc[5] = {0.f, 0.f, 0.f, 0.f, 0.f};
    for (int p = s; p < e; p++) {
        int c = csr[p];
        float w = dinv[c];
        const float* hc = h2 + (size_t)c * NCLS;
#pragma unroll
        for (int i = 0; i < 5; i++) acc[i] = fmaf(w, hc[l + 8 * i], acc[i]);
    }
    float dr = dinv[r];
    const float* hr = h2 + (size_t)r * NCLS;
    float z[5];
#pragma unroll
    for (int i = 0; i < 5; i++)
        z[i] = dr * (acc[i] + dr * hr[l + 8 * i]) + b2[l + 8 * i];

    float m = z[0];
#pragma unroll
    for (int i = 1; i < 5; i++) m = fmaxf(m, z[i]);
#pragma unroll
    for (int off = 1; off < 8; off <<= 1) m = fmaxf(m, __shfl_xor(m, off, 8));
    float ssum = 0.f;
#pragma unroll
    for (int i = 0; i < 5; i++) ssum += __expf(z[i] - m);
#pragma unroll
    for (int off = 1; off < 8; off <<= 1) ssum += __shfl_xor(ssum, off, 8);
    float ls = m + logf(ssum);
#pragma unroll
    for (int i = 0; i < 5; i++) out[(size_t)r * NCLS + l + 8 * i] = z[i] - ls;
}

// ---------------- launch ----------------

extern "C" void kernel_launch(void* const* d_in, const int* in_sizes, int n_in,
                              void* d_out, int out_size, void* d_ws, size_t ws_size,
                              hipStream_t stream) {
    const float* x  = (const float*)d_in[0];
    const int*   ei = (const int*)d_in[1];
    const float* W1 = (const float*)d_in[2];
    const float* b1 = (const float*)d_in[3];
    const float* W2 = (const float*)d_in[4];
    const float* b2 = (const float*)d_in[5];

    const int n = in_sizes[0] / NFEAT;   // 100000
    const int E = in_sizes[1] / 2;       // 3200000
    const int* row = ei;
    const int* col = ei + E;
    const int nb = (n + BROWS - 1) / BROWS;   // 391

    char* w = (char*)d_ws;
    auto alloc = [&](size_t bytes) {
        void* p = (void*)w;
        w += (bytes + 255) & ~(size_t)255;
        return p;
    };
    int*   cnt   = (int*)alloc((size_t)n * 4);
    int*   start = (int*)alloc((size_t)(n + 1) * 4);
    int*   bcnt  = (int*)alloc(2048);
    int*   boff  = (int*)alloc(2048 + 4);
    int*   bcur  = (int*)alloc(2048);
    float* dinv  = (float*)alloc((size_t)n * 4);
    int*   csr   = (int*)alloc((size_t)E * 4);
    int2*  pairs = (int2*)alloc((size_t)E * 8);
    float* h1    = (float*)alloc((size_t)n * HID * 4);
    float* h1b   = (float*)alloc((size_t)n * HID * 4);
    float* h2    = (float*)alloc((size_t)n * NCLS * 4);

    hipMemsetAsync(cnt, 0, (size_t)n * 4, stream);
    k_hist<<<2048, 256, 0, stream>>>(row, cnt, E);
    k_bsum<<<nb, 256, 0, stream>>>(cnt, dinv, bcnt, n);
    k_scan_small<<<1, 512, 0, stream>>>(bcnt, boff, bcur, nb, E);
    k_pairs<<<512, 256, 0, stream>>>(row, col, bcur, pairs, E, nb);
    k_csr<<<nb, 256, 0, stream>>>(cnt, boff, pairs, csr, start, n, E);

    k_gemm1<<<(n + 63) / 64, 64, 0, stream>>>(x, W1, h1, n);
    k_agg1<<<(n + 15) / 16, 256, 0, stream>>>(h1, start, csr, dinv, b1, h1b, n);
    k_gemm2<<<(n + 63) / 64, 64, 0, stream>>>(h1b, W2, h2, n);
    k_agg2<<<(n + 31) / 32, 256, 0, stream>>>(h2, start, csr, dinv, b2, (float*)d_out, n);
}